// Round 1
// baseline (177.535 us; speedup 1.0000x reference)
//
#include <hip/hip_runtime.h>

// Problem constants: b=4, n=2048, dim=64, H=8, D=8, SCALE=0.125
#define NSPLIT 4
#define SPLEN  512   // 2048 / NSPLIT
#define KC     64    // key chunk staged in LDS

// ---------------- K1: qkv = x @ Wqkv + bqkv, scattered to [b*h][n][8] ----------------
__global__ __launch_bounds__(192) void qkv_proj_kernel(
    const float* __restrict__ X, const float* __restrict__ W,
    const float* __restrict__ bias,
    float* __restrict__ Qb, float* __restrict__ Kb, float* __restrict__ Vb)
{
    __shared__ __align__(16) float xsT[64 * 12];   // transposed x tile [k][r], pad 12
    const int row0 = blockIdx.x * 8;
    const int t = threadIdx.x;
    if (t < 64) {
        #pragma unroll
        for (int r = 0; r < 8; ++r)
            xsT[t * 12 + r] = X[(size_t)(row0 + r) * 64 + t];
    }
    __syncthreads();
    const int j = t;               // output column 0..191
    const float bj = bias[j];
    float acc[8];
    #pragma unroll
    for (int r = 0; r < 8; ++r) acc[r] = bj;
    #pragma unroll 4
    for (int k = 0; k < 64; ++k) {
        const float w = W[k * 192 + j];
        const float4 x0 = *(const float4*)&xsT[k * 12];
        const float4 x1 = *(const float4*)&xsT[k * 12 + 4];
        acc[0] = fmaf(x0.x, w, acc[0]);
        acc[1] = fmaf(x0.y, w, acc[1]);
        acc[2] = fmaf(x0.z, w, acc[2]);
        acc[3] = fmaf(x0.w, w, acc[3]);
        acc[4] = fmaf(x1.x, w, acc[4]);
        acc[5] = fmaf(x1.y, w, acc[5]);
        acc[6] = fmaf(x1.z, w, acc[6]);
        acc[7] = fmaf(x1.w, w, acc[7]);
    }
    float* dst = (j < 64) ? Qb : (j < 128) ? Kb : Vb;
    const int c = j & 63;
    const int h = c >> 3, d = c & 7;
    #pragma unroll
    for (int r = 0; r < 8; ++r) {
        const int R = row0 + r;
        const int bi = R >> 11, i = R & 2047;
        dst[(size_t)((bi * 8 + h) * 2048 + i) * 8 + d] = acc[r];
    }
}

// ---------------- K2/K4: split-K attention, one query per lane ----------------
// grid: (bh=32, qtile=8, split=NSPLIT); block 256
// Partials: Part[bh][qi][split][9] = {acc[8], l}.  No max-subtraction needed:
// scores = 0.125 * dot8 of small vectors, |s| << 10, exp cannot overflow.
__global__ __launch_bounds__(256) void attn_split_kernel(
    const float* __restrict__ Qb, const float* __restrict__ Kb,
    const float* __restrict__ Vb, float* __restrict__ Part)
{
    const int bh = blockIdx.x, qt = blockIdx.y, sp = blockIdx.z;
    const int qi = qt * 256 + threadIdx.x;
    const float* qp = Qb + ((size_t)bh * 2048 + qi) * 8;
    const float4 qa = *(const float4*)(qp);
    const float4 qc = *(const float4*)(qp + 4);
    const float sc = 0.125f;
    const float q0 = qa.x * sc, q1 = qa.y * sc, q2 = qa.z * sc, q3 = qa.w * sc;
    const float q4 = qc.x * sc, q5 = qc.y * sc, q6 = qc.z * sc, q7 = qc.w * sc;

    __shared__ __align__(16) float Ks[KC * 8];
    __shared__ __align__(16) float Vs[KC * 8];

    float a0 = 0.f, a1 = 0.f, a2 = 0.f, a3 = 0.f;
    float a4 = 0.f, a5 = 0.f, a6 = 0.f, a7 = 0.f;
    float l = 0.f;

    const size_t kbase = (size_t)bh * 2048 + (size_t)sp * SPLEN;
    for (int kc = 0; kc < SPLEN; kc += KC) {
        const float4* ksrc = (const float4*)(Kb + (kbase + kc) * 8);
        const float4* vsrc = (const float4*)(Vb + (kbase + kc) * 8);
        __syncthreads();   // protect previous chunk's reads
        const int t = threadIdx.x;
        if (t < 128) ((float4*)Ks)[t] = ksrc[t];
        else         ((float4*)Vs)[t - 128] = vsrc[t - 128];
        __syncthreads();
        #pragma unroll 4
        for (int j = 0; j < KC; ++j) {
            const float4 k0 = *(const float4*)&Ks[j * 8];
            const float4 k1 = *(const float4*)&Ks[j * 8 + 4];
            float s = q0 * k0.x;
            s = fmaf(q1, k0.y, s);
            s = fmaf(q2, k0.z, s);
            s = fmaf(q3, k0.w, s);
            s = fmaf(q4, k1.x, s);
            s = fmaf(q5, k1.y, s);
            s = fmaf(q6, k1.z, s);
            s = fmaf(q7, k1.w, s);
            const float p = __expf(s);
            l += p;
            const float4 v0 = *(const float4*)&Vs[j * 8];
            const float4 v1 = *(const float4*)&Vs[j * 8 + 4];
            a0 = fmaf(p, v0.x, a0);
            a1 = fmaf(p, v0.y, a1);
            a2 = fmaf(p, v0.z, a2);
            a3 = fmaf(p, v0.w, a3);
            a4 = fmaf(p, v1.x, a4);
            a5 = fmaf(p, v1.y, a5);
            a6 = fmaf(p, v1.z, a6);
            a7 = fmaf(p, v1.w, a7);
        }
    }
    float* pp = Part + ((size_t)(bh * 2048 + qi) * NSPLIT + sp) * 9;
    pp[0] = a0; pp[1] = a1; pp[2] = a2; pp[3] = a3;
    pp[4] = a4; pp[5] = a5; pp[6] = a6; pp[7] = a7;
    pp[8] = l;
}

// ---------------- C2/C4: combine split partials, write merged [b][n][64] ----------------
__global__ __launch_bounds__(256) void attn_combine_kernel(
    const float* __restrict__ Part, float* __restrict__ M)
{
    const int idx = blockIdx.x * 256 + threadIdx.x;   // 65536 = bh*2048 + qi
    const float* pp = Part + (size_t)idx * (NSPLIT * 9);
    float a[8] = {0.f, 0.f, 0.f, 0.f, 0.f, 0.f, 0.f, 0.f};
    float l = 0.f;
    #pragma unroll
    for (int sp = 0; sp < NSPLIT; ++sp) {
        #pragma unroll
        for (int d = 0; d < 8; ++d) a[d] += pp[sp * 9 + d];
        l += pp[sp * 9 + 8];
    }
    const float inv = 1.0f / l;
    const int bh = idx >> 11, qi = idx & 2047;
    const int b = bh >> 3, h = bh & 7;
    float* op = M + (size_t)(b * 2048 + qi) * 64 + h * 8;
    #pragma unroll
    for (int d = 0; d < 8; ++d) op[d] = a[d] * inv;
}

// ---------------- K3/K5: 64x64 projection. mode 0: scatter to q1 layout, mode 1: plain ----------------
// q1 reshape: p[b,n,64] -> [b,8,n,8]: element (bi,h,i,d) = p[bi, h*256 + i/8, (i%8)*8+d]
// inverse: p row rr, col j -> h=rr>>8, store offset (bi*8+h)*16384 + (rr&255)*64 + j  (coalesced in j)
__global__ __launch_bounds__(64) void proj64_kernel(
    const float* __restrict__ X, const float* __restrict__ W,
    const float* __restrict__ bias, float* __restrict__ Out, int mode)
{
    __shared__ __align__(16) float xsT[64 * 12];
    const int row0 = blockIdx.x * 8;
    const int c = threadIdx.x;
    #pragma unroll
    for (int r = 0; r < 8; ++r)
        xsT[c * 12 + r] = X[(size_t)(row0 + r) * 64 + c];
    __syncthreads();
    const float bc = bias[c];
    float acc[8];
    #pragma unroll
    for (int r = 0; r < 8; ++r) acc[r] = bc;
    #pragma unroll 4
    for (int k = 0; k < 64; ++k) {
        const float w = W[k * 64 + c];
        const float4 x0 = *(const float4*)&xsT[k * 12];
        const float4 x1 = *(const float4*)&xsT[k * 12 + 4];
        acc[0] = fmaf(x0.x, w, acc[0]);
        acc[1] = fmaf(x0.y, w, acc[1]);
        acc[2] = fmaf(x0.z, w, acc[2]);
        acc[3] = fmaf(x0.w, w, acc[3]);
        acc[4] = fmaf(x1.x, w, acc[4]);
        acc[5] = fmaf(x1.y, w, acc[5]);
        acc[6] = fmaf(x1.z, w, acc[6]);
        acc[7] = fmaf(x1.w, w, acc[7]);
    }
    if (mode == 0) {
        #pragma unroll
        for (int r = 0; r < 8; ++r) {
            const int R = row0 + r;
            const int bi = R >> 11, rr = R & 2047;
            const int h = rr >> 8;
            Out[(size_t)(bi * 8 + h) * 16384 + (size_t)(rr & 255) * 64 + c] = acc[r];
        }
    } else {
        #pragma unroll
        for (int r = 0; r < 8; ++r)
            Out[(size_t)(row0 + r) * 64 + c] = acc[r];
    }
}

extern "C" void kernel_launch(void* const* d_in, const int* in_sizes, int n_in,
                              void* d_out, int out_size, void* d_ws, size_t ws_size,
                              hipStream_t stream) {
    const float* x    = (const float*)d_in[0];
    const float* Wqkv = (const float*)d_in[1];
    const float* bqkv = (const float*)d_in[2];
    const float* W1   = (const float*)d_in[3];
    const float* b1   = (const float*)d_in[4];
    float* out = (float*)d_out;
    float* ws  = (float*)d_ws;

    // workspace layout (floats)
    float* Qb   = ws;                 // 524288
    float* Kb   = ws + 524288;        // 524288
    float* Vb   = ws + 1048576;       // 524288
    float* Part = ws + 1572864;       // 32*2048*NSPLIT*9 = 2359296
    float* M1   = ws + 3932160;       // 524288
    float* Q1b  = ws + 4456448;       // 524288
    float* M2   = ws + 4980736;       // 524288  (end: 5505024 floats = 22 MB)

    // Stage 1
    qkv_proj_kernel<<<1024, 192, 0, stream>>>(x, Wqkv, bqkv, Qb, Kb, Vb);
    attn_split_kernel<<<dim3(32, 8, NSPLIT), 256, 0, stream>>>(Qb, Kb, Vb, Part);
    attn_combine_kernel<<<256, 256, 0, stream>>>(Part, M1);
    // Stage 2
    proj64_kernel<<<1024, 64, 0, stream>>>(M1, W1, b1, Q1b, 0);
    attn_split_kernel<<<dim3(32, 8, NSPLIT), 256, 0, stream>>>(Q1b, Q1b, Q1b, Part);
    attn_combine_kernel<<<256, 256, 0, stream>>>(Part, M2);
    proj64_kernel<<<1024, 64, 0, stream>>>(M2, W1, b1, out, 1);
}

// Round 2
// 90.701 us; speedup vs baseline: 1.9574x; 1.9574x over previous
//
#include <hip/hip_runtime.h>
#include <hip/hip_bf16.h>

typedef __attribute__((ext_vector_type(8))) short s8v;
typedef __attribute__((ext_vector_type(4))) short s4v;
typedef __attribute__((ext_vector_type(4))) float fx4;

#define QK_SCALE 0.1803368801111204f  /* 0.125 * log2(e) */

#if __has_builtin(__builtin_amdgcn_exp2f)
#define EXP2(x) __builtin_amdgcn_exp2f(x)
#else
#define EXP2(x) exp2f(x)
#endif

static __device__ __forceinline__ unsigned short f2bf(float f) {
    unsigned int u = __float_as_uint(f);
    u += 0x7fffu + ((u >> 16) & 1u);
    return (unsigned short)(u >> 16);
}
static __device__ __forceinline__ float bf2f(unsigned short h) {
    return __uint_as_float(((unsigned int)h) << 16);
}

static __device__ __forceinline__ fx4 mfma16(s4v a, s4v b, fx4 c) {
#if __has_builtin(__builtin_amdgcn_mfma_f32_16x16x16bf16_1k)
    return __builtin_amdgcn_mfma_f32_16x16x16bf16_1k(a, b, c, 0, 0, 0);
#else
    asm("v_mfma_f32_16x16x16_bf16 %0, %1, %2, %3" : "=v"(c) : "v"(a), "v"(b), "v"(c));
    return c;
#endif
}

// ---------------- K1: qkv = x @ Wqkv + bqkv, scattered to [b*h][n][8] ----------------
__global__ __launch_bounds__(192) void qkv_proj_kernel(
    const float* __restrict__ X, const float* __restrict__ W,
    const float* __restrict__ bias,
    float* __restrict__ Qb, float* __restrict__ Kb, float* __restrict__ Vb)
{
    __shared__ __align__(16) float xsT[64 * 12];
    const int row0 = blockIdx.x * 8;
    const int t = threadIdx.x;
    if (t < 64) {
        #pragma unroll
        for (int r = 0; r < 8; ++r)
            xsT[t * 12 + r] = X[(size_t)(row0 + r) * 64 + t];
    }
    __syncthreads();
    const int j = t;
    const float bj = bias[j];
    float acc[8];
    #pragma unroll
    for (int r = 0; r < 8; ++r) acc[r] = bj;
    #pragma unroll 4
    for (int k = 0; k < 64; ++k) {
        const float w = W[k * 192 + j];
        const float4 x0 = *(const float4*)&xsT[k * 12];
        const float4 x1 = *(const float4*)&xsT[k * 12 + 4];
        acc[0] = fmaf(x0.x, w, acc[0]);
        acc[1] = fmaf(x0.y, w, acc[1]);
        acc[2] = fmaf(x0.z, w, acc[2]);
        acc[3] = fmaf(x0.w, w, acc[3]);
        acc[4] = fmaf(x1.x, w, acc[4]);
        acc[5] = fmaf(x1.y, w, acc[5]);
        acc[6] = fmaf(x1.z, w, acc[6]);
        acc[7] = fmaf(x1.w, w, acc[7]);
    }
    float* dst = (j < 64) ? Qb : (j < 128) ? Kb : Vb;
    const int c = j & 63;
    const int h = c >> 3, d = c & 7;
    #pragma unroll
    for (int r = 0; r < 8; ++r) {
        const int R = row0 + r;
        const int bi = R >> 11, i = R & 2047;
        dst[(size_t)((bi * 8 + h) * 2048 + i) * 8 + d] = acc[r];
    }
}

// ---------------- MFMA flash attention (both stages) ----------------
// grid (bh=32, qt=32), block 256 = 4 waves, 64 q-rows per block, 16 per wave.
// QK^T: mfma_16x16x32_bf16, A=K hi/lo packed [khi,klo,khi,0], B=Q [qhi,qhi,qlo,0]
//   -> C = S^T: lane: col=q=l&15, row=key=4*(l>>4)+r  (scale*log2e folded into Q)
// P = exp2(S^T) -> bf16: exactly the B-frag of mfma_16x16x16_bf16 (k=4*(l>>4)+j)
// PV: O^T = A_V * P^T with A_V = [V^T rows d=0..7; ones row d=8] -> row 8 = sum(P) = l
__global__ __launch_bounds__(256) void attn_mfma_kernel(
    const float* __restrict__ Qb, const float* __restrict__ Kb,
    const float* __restrict__ Vb, float* __restrict__ M)
{
    __shared__ unsigned short Khl[64 * 24];  // per key: [hi x8 | lo x8 | pad x8], 48B stride
    __shared__ unsigned short Vt[16 * 72];   // V^T rows d=0..7, ones row 8, pad stride 72

    const int bh = blockIdx.x, qt = blockIdx.y;
    const int tid = threadIdx.x;
    const int w = tid >> 6, l = tid & 63;
    const int g = l >> 4, ql = l & 15;
    const int qglob = qt * 64 + w * 16 + ql;

    // ---- Q fragment (B operand of QK mfma), scale folded in ----
    s8v bq;
    {
        const float* qp = Qb + ((size_t)bh * 2048 + qglob) * 8;
        float4 qa = *(const float4*)qp;
        float4 qc = *(const float4*)(qp + 4);
        float qs[8] = {qa.x, qa.y, qa.z, qa.w, qc.x, qc.y, qc.z, qc.w};
        #pragma unroll
        for (int d = 0; d < 8; ++d) {
            float v = qs[d] * QK_SCALE;
            unsigned short hh = f2bf(v);
            unsigned short ll = f2bf(v - bf2f(hh));
            short e = (g < 2) ? (short)hh : (g == 2) ? (short)ll : (short)0;
            bq[d] = e;
        }
    }

    // ones row (d=8) of V^T: 1.0bf16 pairs, persists across chunks
    if (tid < 32) ((unsigned int*)Vt)[288 + tid] = 0x3f803f80u;

    const int key = tid >> 2, dp = (tid & 3) * 2;
    const size_t kvbh = (size_t)bh * 16384;  // 2048 * 8
    const float2* ksrc = (const float2*)(Kb + kvbh);
    const float2* vsrc = (const float2*)(Vb + kvbh);
    float2 kreg = ksrc[tid];
    float2 vreg = vsrc[tid];

    const unsigned short* akp = &Khl[ql * 24 + ((g == 1) ? 8 : 0)];
    const unsigned short* avp = &Vt[ql * 72 + g * 4];

    fx4 accO = {0.f, 0.f, 0.f, 0.f};
    const fx4 zf = {0.f, 0.f, 0.f, 0.f};

    for (int c = 0; c < 32; ++c) {
        // convert staged regs -> LDS
        {
            unsigned short hx = f2bf(kreg.x), hy = f2bf(kreg.y);
            unsigned int hp = (unsigned int)hx | ((unsigned int)hy << 16);
            unsigned int lp = (unsigned int)f2bf(kreg.x - bf2f(hx)) |
                              ((unsigned int)f2bf(kreg.y - bf2f(hy)) << 16);
            unsigned int* kd = (unsigned int*)Khl;
            kd[key * 12 + (dp >> 1)] = hp;
            kd[key * 12 + 4 + (dp >> 1)] = lp;
            Vt[dp * 72 + key] = f2bf(vreg.x);
            Vt[(dp + 1) * 72 + key] = f2bf(vreg.y);
        }
        __syncthreads();
        if (c + 1 < 32) {
            kreg = ksrc[(c + 1) * 256 + tid];
            vreg = vsrc[(c + 1) * 256 + tid];
        }
        #pragma unroll
        for (int kg = 0; kg < 4; ++kg) {
            s8v ak = *(const s8v*)(akp + kg * 384);
            fx4 s = __builtin_amdgcn_mfma_f32_16x16x32_bf16(ak, bq, zf, 0, 0, 0);
            float p0 = EXP2(s[0]), p1 = EXP2(s[1]), p2 = EXP2(s[2]), p3 = EXP2(s[3]);
            s4v bp;
            bp[0] = (short)f2bf(p0); bp[1] = (short)f2bf(p1);
            bp[2] = (short)f2bf(p2); bp[3] = (short)f2bf(p3);
            s4v av = *(const s4v*)(avp + kg * 16);
            accO = mfma16(av, bp, accO);
        }
        __syncthreads();
    }

    // softmax denominator: O^T row 8 lives at lanes 32..47 (reg 0), col q
    int lv_i = __builtin_amdgcn_ds_bpermute((32 + ql) * 4, __float_as_int(accO[0]));
    float lv = __int_as_float(lv_i);
    if (g < 2) {
        const float inv = 1.0f / lv;
        const int b = bh >> 3, h = bh & 7;
        float4 o = {accO[0] * inv, accO[1] * inv, accO[2] * inv, accO[3] * inv};
        *(float4*)(M + ((size_t)(b * 2048 + qglob)) * 64 + h * 8 + g * 4) = o;
    }
}

// ---------------- proj64: 64x64 projection. mode 0: scatter to q1 layout, mode 1: plain ----------------
__global__ __launch_bounds__(64) void proj64_kernel(
    const float* __restrict__ X, const float* __restrict__ W,
    const float* __restrict__ bias, float* __restrict__ Out, int mode)
{
    __shared__ __align__(16) float xsT[64 * 12];
    const int row0 = blockIdx.x * 8;
    const int c = threadIdx.x;
    #pragma unroll
    for (int r = 0; r < 8; ++r)
        xsT[c * 12 + r] = X[(size_t)(row0 + r) * 64 + c];
    __syncthreads();
    const float bc = bias[c];
    float acc[8];
    #pragma unroll
    for (int r = 0; r < 8; ++r) acc[r] = bc;
    #pragma unroll 4
    for (int k = 0; k < 64; ++k) {
        const float w = W[k * 64 + c];
        const float4 x0 = *(const float4*)&xsT[k * 12];
        const float4 x1 = *(const float4*)&xsT[k * 12 + 4];
        acc[0] = fmaf(x0.x, w, acc[0]);
        acc[1] = fmaf(x0.y, w, acc[1]);
        acc[2] = fmaf(x0.z, w, acc[2]);
        acc[3] = fmaf(x0.w, w, acc[3]);
        acc[4] = fmaf(x1.x, w, acc[4]);
        acc[5] = fmaf(x1.y, w, acc[5]);
        acc[6] = fmaf(x1.z, w, acc[6]);
        acc[7] = fmaf(x1.w, w, acc[7]);
    }
    if (mode == 0) {
        #pragma unroll
        for (int r = 0; r < 8; ++r) {
            const int R = row0 + r;
            const int bi = R >> 11, rr = R & 2047;
            const int h = rr >> 8;
            Out[(size_t)(bi * 8 + h) * 16384 + (size_t)(rr & 255) * 64 + c] = acc[r];
        }
    } else {
        #pragma unroll
        for (int r = 0; r < 8; ++r)
            Out[(size_t)(row0 + r) * 64 + c] = acc[r];
    }
}

extern "C" void kernel_launch(void* const* d_in, const int* in_sizes, int n_in,
                              void* d_out, int out_size, void* d_ws, size_t ws_size,
                              hipStream_t stream) {
    const float* x    = (const float*)d_in[0];
    const float* Wqkv = (const float*)d_in[1];
    const float* bqkv = (const float*)d_in[2];
    const float* W1   = (const float*)d_in[3];
    const float* b1   = (const float*)d_in[4];
    float* out = (float*)d_out;
    float* ws  = (float*)d_ws;

    float* Qb  = ws;                  // 524288 floats
    float* Kb  = ws + 524288;
    float* Vb  = ws + 1048576;
    float* M1  = ws + 1572864;
    float* Q1b = ws + 2097152;
    float* M2  = ws + 2621440;        // end: 3145728 floats = 12 MB

    qkv_proj_kernel<<<1024, 192, 0, stream>>>(x, Wqkv, bqkv, Qb, Kb, Vb);
    attn_mfma_kernel<<<dim3(32, 32), 256, 0, stream>>>(Qb, Kb, Vb, M1);
    proj64_kernel<<<1024, 64, 0, stream>>>(M1, W1, b1, Q1b, 0);
    attn_mfma_kernel<<<dim3(32, 32), 256, 0, stream>>>(Q1b, Q1b, Q1b, M2);
    proj64_kernel<<<1024, 64, 0, stream>>>(M2, W1, b1, out, 1);
}